// Round 4
// baseline (5790.102 us; speedup 1.0000x reference)
//
#include <hip/hip_runtime.h>
#include <hip/hip_bf16.h>

// B=64, T=512, D=512, H=512, 3H=1536. fp32 I/O; bf16 MFMA operands.
#define B_ 64
#define T_ 512
#define D_ 512
#define H_ 512
#define G3 1536
#define NBLK 16          // persistent blocks: 96 gate-cols (GEMM) + 4 samples (PW) each

typedef float f32x4 __attribute__((ext_vector_type(4)));
typedef __bf16 bf16x8 __attribute__((ext_vector_type(8)));

#define LDSP 56          // k1 LDS pitch (bf16 elems)
#define WPITCH 520       // k2 w-slice LDS pitch (bf16 elems)

union bfpack { bf16x8 v; __hip_bfloat16 h[8]; };

__device__ inline bf16x8 cvt8(const float* __restrict__ p) {
    float4 f0 = *(const float4*)p;
    float4 f1 = *(const float4*)(p + 4);
    bfpack u;
    u.h[0] = __float2bfloat16(f0.x); u.h[1] = __float2bfloat16(f0.y);
    u.h[2] = __float2bfloat16(f0.z); u.h[3] = __float2bfloat16(f0.w);
    u.h[4] = __float2bfloat16(f1.x); u.h[5] = __float2bfloat16(f1.y);
    u.h[6] = __float2bfloat16(f1.z); u.h[7] = __float2bfloat16(f1.w);
    return u.v;
}

// ---------------- K0: init HB (h bf16) + zero barrier counters ---------------
__global__ void k0_init(const float* __restrict__ h_in,
                        __hip_bfloat16* __restrict__ hb,
                        unsigned int* __restrict__ ctr) {
    int i = blockIdx.x * blockDim.x + threadIdx.x;
    if (i < B_ * H_) hb[i] = __float2bfloat16(h_in[i]);
    if (i < 1024)    ctr[i] = 0u;
}

// ---------------- K1: XG = x @ w_ih^T + b_ih (MFMA 128x128, bf16 out) --------
__global__ __launch_bounds__(256) void k1_xgemm(
    const float* __restrict__ X, const float* __restrict__ W,
    const float* __restrict__ bias, __hip_bfloat16* __restrict__ XG)
{
    __shared__ __align__(16) __hip_bfloat16 la[128 * LDSP];
    __shared__ __align__(16) __hip_bfloat16 lb[128 * LDSP];
    int tid = threadIdx.x, bx = blockIdx.x;
    int m0 = (bx / 12) * 128, n0 = (bx % 12) * 128;
    int wave = tid >> 6, lane = tid & 63;
    int wh = wave >> 1, ww = wave & 1;
    int l15 = lane & 15, kq = lane >> 4;

    f32x4 acc[4][4];
    #pragma unroll
    for (int i = 0; i < 4; i++)
        #pragma unroll
        for (int j = 0; j < 4; j++) acc[i][j] = (f32x4){0.f, 0.f, 0.f, 0.f};

    for (int kt = 0; kt < 16; ++kt) {
        int k0 = kt * 32;
        for (int s = tid; s < 512; s += 256) {
            int r = s >> 2, c = s & 3;
            *(bf16x8*)&la[r * LDSP + c * 8] = cvt8(&X[(size_t)(m0 + r) * D_ + k0 + c * 8]);
            *(bf16x8*)&lb[r * LDSP + c * 8] = cvt8(&W[(size_t)(n0 + r) * D_ + k0 + c * 8]);
        }
        __syncthreads();
        bf16x8 af[4], bq[4];
        #pragma unroll
        for (int i = 0; i < 4; i++)
            af[i] = *(const bf16x8*)&la[(wh * 64 + i * 16 + l15) * LDSP + kq * 8];
        #pragma unroll
        for (int j = 0; j < 4; j++)
            bq[j] = *(const bf16x8*)&lb[(ww * 64 + j * 16 + l15) * LDSP + kq * 8];
        #pragma unroll
        for (int i = 0; i < 4; i++)
            #pragma unroll
            for (int j = 0; j < 4; j++)
                acc[i][j] = __builtin_amdgcn_mfma_f32_16x16x32_bf16(af[i], bq[j], acc[i][j], 0, 0, 0);
        __syncthreads();
    }
    #pragma unroll
    for (int i = 0; i < 4; i++)
        #pragma unroll
        for (int j = 0; j < 4; j++)
            #pragma unroll
            for (int r = 0; r < 4; r++) {
                int m = m0 + wh * 64 + i * 16 + kq * 4 + r;
                int n = n0 + ww * 64 + j * 16 + l15;
                int b = m >> 9, t = m & 511;
                XG[((size_t)t * B_ + b) * G3 + n] = __float2bfloat16(acc[i][j][r] + bias[n]);
            }
}

// ---------------- K2: persistent recurrence kernel ---------------------------
// 16 blocks x 512 threads. GEMM: block computes HG cols [96i,96i+96), w-slice
// LDS-resident. Pointwise: wave-per-sample (waves 0-3 own samples 4i..4i+3),
// 8 contiguous cols/lane, butterfly-shuffle LN reductions (no LDS).
// Barriers: RELEASE arrive -> overlap local work -> RELAXED spin -> ACQUIRE fence.
__global__ __launch_bounds__(512, 1) void k2_recur(
    const float* __restrict__ h_in, const float* __restrict__ Whh,
    const float* __restrict__ b_hh,
    const float* __restrict__ lnrw, const float* __restrict__ lnrb,
    const float* __restrict__ lnzw, const float* __restrict__ lnzb,
    const float* __restrict__ lnnw, const float* __restrict__ lnnb,
    const __hip_bfloat16* __restrict__ XG,
    float* __restrict__ HG, __hip_bfloat16* __restrict__ HB,
    unsigned int* __restrict__ ctr, float* __restrict__ out)
{
    __shared__ __align__(16) __hip_bfloat16 lw[96 * WPITCH]; // 99,840 B

    const int tid = threadIdx.x;
    const int blk = blockIdx.x;
    const int n0 = blk * 96;   // GEMM gate-column slice base
    const int s0 = blk * 4;    // pointwise sample base

    // one-time: stage w_hh slice fp32->bf16 into LDS
    for (int idx = tid; idx < 96 * 64; idx += 512) {
        int row = idx >> 6, ch = idx & 63;
        *(bf16x8*)&lw[row * WPITCH + ch * 8] = cvt8(&Whh[(size_t)(n0 + row) * H_ + ch * 8]);
    }

    const int w = tid >> 6, lane = tid & 63;
    const int l15 = lane & 15, kq = lane >> 4;
    const int mt = w >> 1;             // GEMM m-tile 0..3
    const int nj0 = (w & 1) * 3;       // 3 n-tiles per wave

    // pointwise role (waves 0-3): sample b, cols c0..c0+7 (contiguous)
    const int b = s0 + w;
    const int c0 = lane * 8;

    float bhr[8], bhz[8], bhn[8], wr[8], br_[8], wz[8], bz_[8], wn[8], bn_[8], hf[8];
    if (w < 4) {
        #pragma unroll
        for (int q = 0; q < 2; q++) {
            float4 t0 = *(const float4*)&b_hh[c0 + 4 * q];
            float4 t1 = *(const float4*)&b_hh[512 + c0 + 4 * q];
            float4 t2 = *(const float4*)&b_hh[1024 + c0 + 4 * q];
            float4 t3 = *(const float4*)&lnrw[c0 + 4 * q];
            float4 t4 = *(const float4*)&lnrb[c0 + 4 * q];
            float4 t5 = *(const float4*)&lnzw[c0 + 4 * q];
            float4 t6 = *(const float4*)&lnzb[c0 + 4 * q];
            float4 t7 = *(const float4*)&lnnw[c0 + 4 * q];
            float4 t8 = *(const float4*)&lnnb[c0 + 4 * q];
            float4 t9 = *(const float4*)&h_in[b * H_ + c0 + 4 * q];
            bhr[4*q]=t0.x; bhr[4*q+1]=t0.y; bhr[4*q+2]=t0.z; bhr[4*q+3]=t0.w;
            bhz[4*q]=t1.x; bhz[4*q+1]=t1.y; bhz[4*q+2]=t1.z; bhz[4*q+3]=t1.w;
            bhn[4*q]=t2.x; bhn[4*q+1]=t2.y; bhn[4*q+2]=t2.z; bhn[4*q+3]=t2.w;
            wr [4*q]=t3.x; wr [4*q+1]=t3.y; wr [4*q+2]=t3.z; wr [4*q+3]=t3.w;
            br_[4*q]=t4.x; br_[4*q+1]=t4.y; br_[4*q+2]=t4.z; br_[4*q+3]=t4.w;
            wz [4*q]=t5.x; wz [4*q+1]=t5.y; wz [4*q+2]=t5.z; wz [4*q+3]=t5.w;
            bz_[4*q]=t6.x; bz_[4*q+1]=t6.y; bz_[4*q+2]=t6.z; bz_[4*q+3]=t6.w;
            wn [4*q]=t7.x; wn [4*q+1]=t7.y; wn [4*q+2]=t7.z; wn [4*q+3]=t7.w;
            bn_[4*q]=t8.x; bn_[4*q+1]=t8.y; bn_[4*q+2]=t8.z; bn_[4*q+3]=t8.w;
            hf [4*q]=t9.x; hf [4*q+1]=t9.y; hf [4*q+2]=t9.z; hf [4*q+3]=t9.w;
        }
    }
    __syncthreads();

    const float inv = 1.0f / 512.0f;

    for (int t = 0; t < T_; ++t) {
        // ================= GEMM: HG slice = h @ w_slice^T ====================
        bf16x8 afr[16];
        {
            const __hip_bfloat16* hrow = HB + (mt * 16 + l15) * H_ + kq * 8;
            #pragma unroll
            for (int kt = 0; kt < 16; kt++) afr[kt] = *(const bf16x8*)(hrow + kt * 32);
        }
        f32x4 a0 = {0,0,0,0}, a1 = {0,0,0,0}, a2 = {0,0,0,0};
        #pragma unroll
        for (int kt = 0; kt < 16; kt++) {
            bf16x8 b0 = *(const bf16x8*)&lw[((nj0    ) * 16 + l15) * WPITCH + kt * 32 + kq * 8];
            bf16x8 b1 = *(const bf16x8*)&lw[((nj0 + 1) * 16 + l15) * WPITCH + kt * 32 + kq * 8];
            bf16x8 b2 = *(const bf16x8*)&lw[((nj0 + 2) * 16 + l15) * WPITCH + kt * 32 + kq * 8];
            a0 = __builtin_amdgcn_mfma_f32_16x16x32_bf16(afr[kt], b0, a0, 0, 0, 0);
            a1 = __builtin_amdgcn_mfma_f32_16x16x32_bf16(afr[kt], b1, a1, 0, 0, 0);
            a2 = __builtin_amdgcn_mfma_f32_16x16x32_bf16(afr[kt], b2, a2, 0, 0, 0);
        }
        {
            int rowb = mt * 16 + kq * 4;
            int colb = n0 + nj0 * 16 + l15;
            #pragma unroll
            for (int r = 0; r < 4; r++) {
                HG[(rowb + r) * G3 + colb     ] = a0[r];
                HG[(rowb + r) * G3 + colb + 16] = a1[r];
                HG[(rowb + r) * G3 + colb + 32] = a2[r];
            }
        }
        // ---- barrier A: arrive (release) -> overlap XG prefetch -> spin -----
        __syncthreads();   // drains all waves' vmcnt; HG stores complete in L2
        if (tid == 0)
            __hip_atomic_fetch_add(&ctr[2 * t], 1u, __ATOMIC_RELEASE, __HIP_MEMORY_SCOPE_AGENT);
        bf16x8 xr8 = {}, xz8 = {}, xn8 = {};
        if (w < 4) {   // XG(t) prefetch: no cross-block dependency, hide under spin
            const __hip_bfloat16* xgrow = XG + ((size_t)t * B_ + b) * G3;
            xr8 = *(const bf16x8*)&xgrow[c0];
            xz8 = *(const bf16x8*)&xgrow[512 + c0];
            xn8 = *(const bf16x8*)&xgrow[1024 + c0];
        }
        if (tid == 0)
            while (__hip_atomic_load(&ctr[2 * t], __ATOMIC_RELAXED, __HIP_MEMORY_SCOPE_AGENT) < NBLK) {}
        __builtin_amdgcn_fence(__ATOMIC_ACQUIRE, "agent");  // single L1/L2 invalidate
        __syncthreads();

        // ================= pointwise (waves 0-3, one sample each) ============
        float hnew[8];
        if (w < 4) {
            const float* hgb = HG + (size_t)b * G3;
            float hr[8], hz[8], hn[8];
            #pragma unroll
            for (int q = 0; q < 2; q++) {
                float4 r4 = *(const float4*)&hgb[c0 + 4 * q];
                float4 z4 = *(const float4*)&hgb[512 + c0 + 4 * q];
                float4 n4 = *(const float4*)&hgb[1024 + c0 + 4 * q];
                hr[4*q]=r4.x; hr[4*q+1]=r4.y; hr[4*q+2]=r4.z; hr[4*q+3]=r4.w;
                hz[4*q]=z4.x; hz[4*q+1]=z4.y; hz[4*q+2]=z4.z; hz[4*q+3]=z4.w;
                hn[4*q]=n4.x; hn[4*q+1]=n4.y; hn[4*q+2]=n4.z; hn[4*q+3]=n4.w;
            }
            bfpack xr, xz, xn; xr.v = xr8; xz.v = xz8; xn.v = xn8;
            float ar[8], az[8], anv[8];
            float sr = 0.f, ssr = 0.f, sz = 0.f, ssz = 0.f;
            #pragma unroll
            for (int j = 0; j < 8; j++) {
                ar[j] = __bfloat162float(xr.h[j]) + hr[j] + bhr[j];
                az[j] = __bfloat162float(xz.h[j]) + hz[j] + bhz[j];
                sr += ar[j]; ssr += ar[j] * ar[j];
                sz += az[j]; ssz += az[j] * az[j];
            }
            #pragma unroll
            for (int off = 32; off; off >>= 1) {
                sr += __shfl_xor(sr, off); ssr += __shfl_xor(ssr, off);
                sz += __shfl_xor(sz, off); ssz += __shfl_xor(ssz, off);
            }
            float mr = sr * inv, vr = ssr * inv - mr * mr, rstd_r = rsqrtf(vr + 1e-5f);
            float mz = sz * inv, vz = ssz * inv - mz * mz, rstd_z = rsqrtf(vz + 1e-5f);
            float rg[8], zg[8];
            float sn = 0.f, ssn = 0.f;
            #pragma unroll
            for (int j = 0; j < 8; j++) {
                rg[j] = 1.f / (1.f + __expf(-((ar[j] - mr) * rstd_r * wr[j] + br_[j])));
                zg[j] = 1.f / (1.f + __expf(-((az[j] - mz) * rstd_z * wz[j] + bz_[j])));
                anv[j] = __bfloat162float(xn.h[j]) + rg[j] * (hn[j] + bhn[j]);
                sn += anv[j]; ssn += anv[j] * anv[j];
            }
            #pragma unroll
            for (int off = 32; off; off >>= 1) {
                sn += __shfl_xor(sn, off); ssn += __shfl_xor(ssn, off);
            }
            float mn = sn * inv, vn = ssn * inv - mn * mn, rstd_n = rsqrtf(vn + 1e-5f);
            bfpack hb8;
            #pragma unroll
            for (int j = 0; j < 8; j++) {
                float ng = tanhf((anv[j] - mn) * rstd_n * wn[j] + bn_[j]);
                hnew[j] = (1.f - zg[j]) * ng + zg[j] * hf[j];
                hf[j] = hnew[j];
                hb8.h[j] = __float2bfloat16(hnew[j]);
            }
            *(bf16x8*)&HB[b * H_ + c0] = hb8.v;
        }
        // ---- barrier B: arrive -> overlap out stores -> spin ----------------
        __syncthreads();
        if (tid == 0)
            __hip_atomic_fetch_add(&ctr[2 * t + 1], 1u, __ATOMIC_RELEASE, __HIP_MEMORY_SCOPE_AGENT);
        if (w < 4) {   // out rows are block-private: fire-and-forget under spin
            float* op = out + ((size_t)b * T_ + t) * H_ + c0;
            *(float4*)op       = make_float4(hnew[0], hnew[1], hnew[2], hnew[3]);
            *(float4*)(op + 4) = make_float4(hnew[4], hnew[5], hnew[6], hnew[7]);
            if (t == T_ - 1) {
                float* fp = out + (size_t)B_ * T_ * H_ + b * H_ + c0;
                *(float4*)fp       = make_float4(hnew[0], hnew[1], hnew[2], hnew[3]);
                *(float4*)(fp + 4) = make_float4(hnew[4], hnew[5], hnew[6], hnew[7]);
            }
        }
        if (tid == 0)
            while (__hip_atomic_load(&ctr[2 * t + 1], __ATOMIC_RELAXED, __HIP_MEMORY_SCOPE_AGENT) < NBLK) {}
        __builtin_amdgcn_fence(__ATOMIC_ACQUIRE, "agent");
        __syncthreads();
    }
}

extern "C" void kernel_launch(void* const* d_in, const int* in_sizes, int n_in,
                              void* d_out, int out_size, void* d_ws, size_t ws_size,
                              hipStream_t stream)
{
    const float* x    = (const float*)d_in[0];
    const float* h    = (const float*)d_in[1];
    const float* w_ih = (const float*)d_in[2];
    const float* b_ih = (const float*)d_in[3];
    const float* w_hh = (const float*)d_in[4];
    const float* b_hh = (const float*)d_in[5];
    const float* lnrw = (const float*)d_in[6];
    const float* lnrb = (const float*)d_in[7];
    const float* lnzw = (const float*)d_in[8];
    const float* lnzb = (const float*)d_in[9];
    const float* lnnw = (const float*)d_in[10];
    const float* lnnb = (const float*)d_in[11];
    float* out = (float*)d_out;

    // ws layout (bytes):
    //   XG  bf16 [512][64][1536] = 100,663,296 @ 0
    //   HG  f32  [64][1536]      =     393,216 @ 100,663,296
    //   HB  bf16 [64][512]       =      65,536 @ 101,056,512
    //   CTR u32  [1024]          =       4,096 @ 101,122,048
    char* ws = (char*)d_ws;
    __hip_bfloat16* XG = (__hip_bfloat16*)ws;
    float*          HG = (float*)(ws + 100663296);
    __hip_bfloat16* HB = (__hip_bfloat16*)(ws + 101056512);
    unsigned int*  CTR = (unsigned int*)(ws + 101122048);

    k0_init<<<128, 256, 0, stream>>>(h, HB, CTR);
    k1_xgemm<<<3072, 256, 0, stream>>>(x, w_ih, b_ih, XG);
    k2_recur<<<NBLK, 512, 0, stream>>>(h, w_hh, b_hh,
        lnrw, lnrb, lnzw, lnzb, lnnw, lnnb, XG, HG, HB, CTR, out);
}